// Round 17
// baseline (349.605 us; speedup 1.0000x reference)
//
#include <hip/hip_runtime.h>
#include <hip/hip_bf16.h>
#include <math.h>

#define NN 20000
#define MP 20032            // NN padded to 64 (MFMA row tiles)
#define NE 320000

typedef __hip_bfloat16 bf16;
typedef __attribute__((ext_vector_type(8))) short short8v;   // 8 bf16 (4 VGPR)
typedef __attribute__((ext_vector_type(4))) short short4v;
typedef __attribute__((ext_vector_type(4))) float f32x4;

__device__ __forceinline__ float b2f(bf16 v){ return __bfloat162float(v); }
__device__ __forceinline__ bf16 f2b(float v){ return __float2bfloat16(v); }
__device__ __forceinline__ float bfbits(short s){
  return __uint_as_float(((unsigned)(unsigned short)s) << 16);
}
__device__ __forceinline__ int clampi(int v, int lo, int hi){ return v < lo ? lo : (v > hi ? hi : v); }
__device__ __forceinline__ void stv(bf16* p, float v){ *p = f2b(v); }
__device__ __forceinline__ void stv(float* p, float v){ *p = v; }
__device__ __forceinline__ float ldv(const bf16* p){ return b2f(*p); }
__device__ __forceinline__ float ldv(const float* p){ return *p; }

// fast erf: Abramowitz-Stegun 7.1.26, |err| <= 1.5e-7
__device__ __forceinline__ float fast_erf(float x){
  float ax = fabsf(x);
  float t = __builtin_amdgcn_rcpf(1.f + 0.3275911f*ax);
  float p = ((((1.061405429f*t - 1.453152027f)*t + 1.421413741f)*t
              - 0.284496736f)*t + 0.254829592f)*t;
  float y = 1.f - p*__expf(-ax*ax);
  return copysignf(y, x);
}
__device__ __forceinline__ float gelu_f(float x){
  return 0.5f*x*(1.f + fast_erf(x*0.70710678118654752f));
}

// vector row loader: CPL consecutive bf16 -> f32
template<int CPL>
__device__ __forceinline__ void ldrow(const bf16* p, float* o){
  if constexpr (CPL == 16){
    short8v v0 = *reinterpret_cast<const short8v*>(p);
    short8v v1 = *reinterpret_cast<const short8v*>(p + 8);
#pragma unroll
    for (int j = 0; j < 8; j++){ o[j] = bfbits(v0[j]); o[8+j] = bfbits(v1[j]); }
  } else if constexpr (CPL == 8){
    short8v v = *reinterpret_cast<const short8v*>(p);
#pragma unroll
    for (int j = 0; j < 8; j++) o[j] = bfbits(v[j]);
  } else {
    short4v v = *reinterpret_cast<const short4v*>(p);
#pragma unroll
    for (int j = 0; j < 4; j++) o[j] = bfbits(v[j]);
  }
}
template<int CPL>
__device__ __forceinline__ void ldrowT(const bf16* p, float* o){ ldrow<CPL>(p, o); }
template<int CPL>
__device__ __forceinline__ void ldrowT(const float* p, float* o){
#pragma unroll
  for (int j = 0; j < CPL; j += 4){
    float4 v = *reinterpret_cast<const float4*>(p + j);
    o[j] = v.x; o[j+1] = v.y; o[j+2] = v.z; o[j+3] = v.w;
  }
}

// A-fragment loaders (8 consecutive-k elems per lane)
__device__ __forceinline__ short8v ldA8(const bf16* p){
  return *reinterpret_cast<const short8v*>(p);
}
__device__ __forceinline__ short8v ldA8(const float* p){
  float4 a0 = *reinterpret_cast<const float4*>(p);
  float4 a1 = *reinterpret_cast<const float4*>(p + 4);
  short8v r;
  bf16 b;
  b = f2b(a0.x); r[0] = *(const short*)&b;
  b = f2b(a0.y); r[1] = *(const short*)&b;
  b = f2b(a0.z); r[2] = *(const short*)&b;
  b = f2b(a0.w); r[3] = *(const short*)&b;
  b = f2b(a1.x); r[4] = *(const short*)&b;
  b = f2b(a1.y); r[5] = *(const short*)&b;
  b = f2b(a1.z); r[6] = *(const short*)&b;
  b = f2b(a1.w); r[7] = *(const short*)&b;
  return r;
}

// ---- diagnostic fill ------------------------------------------------------
__global__ void fill_k(float* __restrict__ out, int n, float val){
  int i = blockIdx.x*blockDim.x + threadIdx.x;
  if (i < n) out[i] = val;
}

// ---- all-weights pack: f32 [K x D] -> MFMA B-fragment order bf16 -----------
struct PackArgs {
  const float* w[16];
  unsigned long long off[16];
  int K[16];
  int D[16];
};
__global__ void pack_all(PackArgs pa, bf16* __restrict__ out){
  int wi = blockIdx.y;
  int K = pa.K[wi], D = pa.D[wi];
  int i = blockIdx.x*256 + threadIdx.x;
  if (i >= K*D) return;
  int j = i & 7, l = (i >> 3) & 63;
  int TG = D >> 4;
  int tg = (i >> 9) % TG, s = (i >> 9) / TG;
  int k = s*32 + (l >> 4)*8 + j, n = tg*16 + (l & 15);
  out[pa.off[wi] + i] = f2b(pa.w[wi][(size_t)k*D + n]);
}

// ---- fused QKVS MFMA GEMM: 4 outputs sharing the A matrix ------------------
// K/V write into interleaved KV buffer (row stride ldKV, V base pre-offset).
template<typename AT, typename TS>
__global__ void gemm_qkvs(const AT* __restrict__ X,
    const short8v* __restrict__ WQ, const short8v* __restrict__ WK,
    const short8v* __restrict__ WV, const short8v* __restrict__ WS,
    const float* __restrict__ bQ, const float* __restrict__ bK,
    const float* __restrict__ bV, const float* __restrict__ bS,
    bf16* __restrict__ Qo, bf16* __restrict__ Ko, bf16* __restrict__ Vo,
    TS* __restrict__ So,
    int K, int TG, int ldQ, int ldKV, int ldS, int MstoreS){
  int w = threadIdx.x >> 6, lane = threadIdx.x & 63;
  int n0 = blockIdx.x*64;
  size_t m0 = (size_t)blockIdx.y*64 + w*16;
  int lr = lane & 15, lk = lane >> 4;
  int ar = clampi((int)(m0 + lr), 0, NN-1);
  const AT* xp = X + (size_t)ar*K + lk*8;
  size_t wo = ((size_t)(n0 >> 4))*64 + lane;
  f32x4 acc[4][4];
#pragma unroll
  for (int j = 0; j < 4; j++)
#pragma unroll
    for (int t = 0; t < 4; t++) acc[j][t] = f32x4{0,0,0,0};
  int steps = K >> 5;
  for (int s = 0; s < steps; s++){
    short8v a = ldA8(xp + s*32);
    size_t ro = wo + (size_t)s*TG*64;
#pragma unroll
    for (int t = 0; t < 4; t++){
      size_t idx = ro + t*64;
      acc[0][t] = __builtin_amdgcn_mfma_f32_16x16x32_bf16(a, WQ[idx], acc[0][t], 0, 0, 0);
      acc[1][t] = __builtin_amdgcn_mfma_f32_16x16x32_bf16(a, WK[idx], acc[1][t], 0, 0, 0);
      acc[2][t] = __builtin_amdgcn_mfma_f32_16x16x32_bf16(a, WV[idx], acc[2][t], 0, 0, 0);
      acc[3][t] = __builtin_amdgcn_mfma_f32_16x16x32_bf16(a, WS[idx], acc[3][t], 0, 0, 0);
    }
  }
#pragma unroll
  for (int t = 0; t < 4; t++){
    int col = n0 + t*16 + lr;
    float b0 = bQ[col], b1 = bK[col], b2 = bV[col], b3 = bS[col];
#pragma unroll
    for (int r = 0; r < 4; r++){
      size_t row = m0 + lk*4 + r;
      Qo[row*(size_t)ldQ  + col] = f2b(acc[0][t][r] + b0);
      Ko[row*(size_t)ldKV + col] = f2b(acc[1][t][r] + b1);
      Vo[row*(size_t)ldKV + col] = f2b(acc[2][t][r] + b2);
      if ((int)row < MstoreS) stv(&So[row*(size_t)ldS + col], acc[3][t][r] + b3);
    }
  }
}

// ---- CSR build -------------------------------------------------------------
__global__ void count_k(const int* __restrict__ ei, int* __restrict__ cnt, int E){
  int e = blockIdx.x*blockDim.x + threadIdx.x;
  if (e < E){
    int d = clampi(ei[E + e], 0, NN-1);
    atomicAdd(&cnt[d], 1);
  }
}

__global__ void exscan_k(const int* __restrict__ cnt, int* __restrict__ off,
                         int* __restrict__ cur, int n){
  __shared__ int wtot[16];
  __shared__ int carrysh;
  int tid = threadIdx.x, lane = tid & 63, w = tid >> 6;
  if (tid == 0) carrysh = 0;
  __syncthreads();
  for (int base = 0; base < n; base += 1024){
    int i = base + tid;
    int v = (i < n) ? cnt[i] : 0;
    int s = v;
#pragma unroll
    for (int d = 1; d < 64; d <<= 1){
      int t = __shfl_up(s, d);
      if (lane >= d) s += t;
    }
    if (lane == 63) wtot[w] = s;
    __syncthreads();
    int woff = 0;
    for (int j = 0; j < w; j++) woff += wtot[j];
    int c = carrysh;
    if (i < n){ int val = c + woff + s - v; off[i] = val; cur[i] = val; }
    __syncthreads();
    if (tid == 1023) carrysh = c + woff + s;
    __syncthreads();
  }
  if (threadIdx.x == 0) off[n] = carrysh;
}

__global__ void scatter_k(const int* __restrict__ ei, int* __restrict__ cur,
                          int* __restrict__ perm, int* __restrict__ srcs, int E){
  int e = blockIdx.x*blockDim.x + threadIdx.x;
  if (e >= E) return;
  int s = clampi(ei[e], 0, NN-1);
  int d = clampi(ei[E + e], 0, NN-1);
  int p = atomicAdd(&cur[d], 1);
  if (p >= 0 && p < E){ perm[p] = e; srcs[p] = s; }
}

// ---- head-group attention (L1/L3): one wave per (node, head-group) ---------
// Heads are independent in TransformerConv; each wave handles DG=D/NHG chans.
// Accumulates skip+agg into Xout (bf16) in place; GELU/LN done separately.
template<int D, int H, int NHG>
__global__ void attn_hg(const bf16* __restrict__ Q, const bf16* __restrict__ KV,
                        const int* __restrict__ srcs, const int* __restrict__ offs,
                        bf16* __restrict__ Xout, float scale){
  constexpr int DG  = D/NHG;      // channels per wave
  constexpr int CPL = DG/16;      // channels per lane
  constexpr int LPH = (D/H)/CPL;  // lanes per head
  int node = blockIdx.x*4 + (threadIdx.x >> 6);
  if (node >= NN) return;
  int cb = blockIdx.y*DG;
  int lane = threadIdx.x & 63;
  int hl = lane & 15;
  int slot = lane >> 4;
  float q[CPL];
  {
    float tmp[CPL];
    ldrow<CPL>(Q + (size_t)node*D + cb + hl*CPL, tmp);
#pragma unroll
    for (int j = 0; j < CPL; j++) q[j] = tmp[j] * scale;
  }
  float den = 0.f;
  float acc[CPL];
#pragma unroll
  for (int j = 0; j < CPL; j++) acc[j] = 0.f;
  int s0 = offs[node], e0 = offs[node+1];
  int i = s0 + slot;
  bool vcur = i < e0;
  int sc = vcur ? srcs[i] : 0;
  float kc[CPL], vc[CPL];
  {
    const bf16* base = KV + (size_t)sc*(2*D) + cb + hl*CPL;
    ldrow<CPL>(base, kc); ldrow<CPL>(base + D, vc);
  }
  int iters = (e0 - s0 + 3) >> 2;
  for (int it = 0; it < iters; ++it){
    int inext = i + 4;
    bool vnxt = inext < e0;
    int sn = vnxt ? srcs[inext] : 0;
    float kn[CPL], vn[CPL];
    {
      const bf16* base = KV + (size_t)sn*(2*D) + cb + hl*CPL;
      ldrow<CPL>(base, kn); ldrow<CPL>(base + D, vn);
    }
    float t = 0.f;
#pragma unroll
    for (int j = 0; j < CPL; j++) t += q[j]*kc[j];
#pragma unroll
    for (int o = 1; o < LPH; o <<= 1) t += __shfl_xor(t, o);
    float pe = vcur ? __expf(t) : 0.f;
    den += pe;
#pragma unroll
    for (int j = 0; j < CPL; j++) acc[j] += pe*vc[j];
    vcur = vnxt; i = inext;
#pragma unroll
    for (int j = 0; j < CPL; j++){ kc[j] = kn[j]; vc[j] = vn[j]; }
  }
  den += __shfl_xor(den, 16);
  den += __shfl_xor(den, 32);
#pragma unroll
  for (int j = 0; j < CPL; j++){
    acc[j] += __shfl_xor(acc[j], 16);
    acc[j] += __shfl_xor(acc[j], 32);
  }
  float inv = 1.f/(den + 1e-16f);
  if (slot == 0){
    bf16* oo = Xout + (size_t)node*D + cb + hl*CPL;
#pragma unroll
    for (int j = 0; j < CPL; j++) oo[j] = f2b(b2f(oo[j]) + acc[j]*inv);
  }
}

// ---- standalone fused GELU + LayerNorm (in place, bf16) --------------------
template<int CPL>
__global__ void gelu_ln(bf16* __restrict__ X, const float* __restrict__ G,
                        const float* __restrict__ Bt){
  int node = blockIdx.x*4 + (threadIdx.x >> 6);
  if (node >= NN) return;
  constexpr int D = CPL*64;
  int lane = threadIdx.x & 63;
  bf16* xr = X + (size_t)node*D + lane*CPL;
  float v[CPL]; float s = 0.f;
  {
    float tmp[CPL];
    ldrow<CPL>(xr, tmp);
#pragma unroll
    for (int j = 0; j < CPL; j++){ float ge = gelu_f(tmp[j]); v[j] = ge; s += ge; }
  }
#pragma unroll
  for (int off = 1; off < 64; off <<= 1) s += __shfl_xor(s, off);
  float mu = s * (1.f/D);
  float q = 0.f;
#pragma unroll
  for (int j = 0; j < CPL; j++){ float d = v[j]-mu; q += d*d; }
#pragma unroll
  for (int off = 1; off < 64; off <<= 1) q += __shfl_xor(q, off);
  float inv = 1.f / sqrtf(q*(1.f/D) + 1e-5f);
#pragma unroll
  for (int j = 0; j < CPL; j++){
    int c = lane*CPL + j;
    xr[j] = f2b(G[c]*(v[j]-mu)*inv + Bt[c]);
  }
}

// ---- full-row fused attention + GELU/LN epilogue (L2/L4) -------------------
template<int D, int H, typename TO>
__global__ void fused_attn(const bf16* __restrict__ Q, const bf16* __restrict__ KV,
                           const int* __restrict__ srcs, const int* __restrict__ offs,
                           TO* __restrict__ Xout, int ldO,
                           const float* __restrict__ G, const float* __restrict__ Bt,
                           bf16* __restrict__ LOG, const int* __restrict__ perm,
                           float* __restrict__ attn_out, float scale){
  constexpr int CPL = D/16;
  constexpr int LPH = 16/H;
  int node = blockIdx.x*4 + (threadIdx.x >> 6);
  if (node >= NN) return;
  int lane = threadIdx.x & 63;
  int hl = lane & 15;
  int slot = lane >> 4;
  float q[CPL];
  {
    float tmp[CPL];
    ldrow<CPL>(Q + (size_t)node*D + hl*CPL, tmp);
#pragma unroll
    for (int j = 0; j < CPL; j++) q[j] = tmp[j] * scale;
  }
  float den = 0.f;
  float acc[CPL];
#pragma unroll
  for (int j = 0; j < CPL; j++) acc[j] = 0.f;
  int s0 = offs[node], e0 = offs[node+1];
  int i = s0 + slot;
  bool vcur = i < e0;
  int sc = vcur ? srcs[i] : 0;
  float kc[CPL], vc[CPL];
  {
    const bf16* base = KV + (size_t)sc*(2*D) + hl*CPL;
    ldrow<CPL>(base, kc); ldrow<CPL>(base + D, vc);
  }
  int iters = (e0 - s0 + 3) >> 2;
  for (int it = 0; it < iters; ++it){
    int inext = i + 4;
    bool vnxt = inext < e0;
    int sn = vnxt ? srcs[inext] : 0;
    float kn[CPL], vn[CPL];
    {
      const bf16* base = KV + (size_t)sn*(2*D) + hl*CPL;
      ldrow<CPL>(base, kn); ldrow<CPL>(base + D, vn);
    }
    float t = 0.f;
#pragma unroll
    for (int j = 0; j < CPL; j++) t += q[j]*kc[j];
#pragma unroll
    for (int o = 1; o < LPH; o <<= 1) t += __shfl_xor(t, o);
    if (LOG && vcur && ((hl & (LPH-1)) == 0)) LOG[(size_t)i*H + hl/LPH] = f2b(t);
    float pe = vcur ? __expf(t) : 0.f;
    den += pe;
#pragma unroll
    for (int j = 0; j < CPL; j++) acc[j] += pe*vc[j];
    vcur = vnxt; i = inext;
#pragma unroll
    for (int j = 0; j < CPL; j++){ kc[j] = kn[j]; vc[j] = vn[j]; }
  }
  den += __shfl_xor(den, 16);
  den += __shfl_xor(den, 32);
#pragma unroll
  for (int j = 0; j < CPL; j++){
    acc[j] += __shfl_xor(acc[j], 16);
    acc[j] += __shfl_xor(acc[j], 32);
  }
  float inv = 1.f/(den + 1e-16f);

  // GELU + LN epilogue
  {
    float sk[CPL];
    ldrowT<CPL>(Xout + (size_t)node*ldO + hl*CPL, sk);
    float v[CPL]; float s = 0.f;
#pragma unroll
    for (int j = 0; j < CPL; j++){
      float ge = gelu_f(sk[j] + acc[j]*inv);
      v[j] = ge; s += ge;
    }
#pragma unroll
    for (int o = 1; o < 16; o <<= 1) s += __shfl_xor(s, o);
    float mu = s * (1.f/D);
    float qv = 0.f;
#pragma unroll
    for (int j = 0; j < CPL; j++){ float d2 = v[j]-mu; qv += d2*d2; }
#pragma unroll
    for (int o = 1; o < 16; o <<= 1) qv += __shfl_xor(qv, o);
    float lni = 1.f / sqrtf(qv*(1.f/D) + 1e-5f);
    if (slot == 0){
      TO* oo = Xout + (size_t)node*ldO + hl*CPL;
#pragma unroll
      for (int j = 0; j < CPL; j++){
        int c = hl*CPL + j;
        stv(&oo[j], G[c]*(v[j]-mu)*lni + Bt[c]);
      }
    }
  }

  // alpha scatter epilogue (L2 only)
  if (attn_out){
    asm volatile("s_waitcnt vmcnt(0)" ::: "memory");
    int total = (e0 - s0) * H;
    int it2 = (total + 63) >> 6;
    for (int b = 0; b < it2; b++){
      int idx = b*64 + lane;
      int h = idx & (H-1);
      float dh = __shfl(den, h*LPH);
      if (idx < total){
        int pos = s0 + (idx >> 3);
        float lg = b2f(LOG[(size_t)pos*H + h]);
        attn_out[(size_t)perm[pos]*H + h] = __expf(lg)/(dh + 1e-16f);
      }
    }
  }
}

// ---- tiny fc ----------------------------------------------------------------
__global__ void fc_k(const bf16* __restrict__ X, const float* __restrict__ W,
                     const float* __restrict__ B, float* __restrict__ Out,
                     int K, int D){
  int m = blockIdx.x*4 + (threadIdx.x >> 6);
  int lane = threadIdx.x & 63;
  if (m >= NN || lane >= D) return;
  float acc = B[lane];
  for (int k = 0; k < K; k++) acc += b2f(X[(size_t)m*K + k]) * W[(size_t)k*D + lane];
  Out[(size_t)m*D + lane] = acc;
}

extern "C" void kernel_launch(void* const* d_in, const int* in_sizes, int n_in,
                              void* d_out, int out_size, void* d_ws, size_t ws_size,
                              hipStream_t stream){
  int code = 0;
  if (n_in != 44) code = 100;
  else {
    const int wsz[4] = {32768,16384,16384,32768};
    const int bsz[4] = {256,64,256,128};
    bool ok = in_sizes[0] == NN*128 && in_sizes[1] == 2*NE
           && in_sizes[42] == 640 && in_sizes[43] == 10;
    for (int l = 0; l < 4 && ok; l++){
      for (int j = 0; j < 4; j++)
        ok = ok && in_sizes[2+l*8+j] == wsz[l] && in_sizes[2+l*8+4+j] == bsz[l];
      ok = ok && in_sizes[34+2*l] == bsz[l] && in_sizes[35+2*l] == bsz[l];
    }
    if (!ok) code = 140;
  }
  if (code){
    fill_k<<<((size_t)out_size+255)/256, 256, 0, stream>>>((float*)d_out, out_size, (float)code);
    return;
  }

  const float* x = (const float*)d_in[0];
  const int*   ei = (const int*)d_in[1];
  const float *W[4][4], *Bw[4][4], *lng[4], *lnb[4];
  for (int l = 0; l < 4; l++){
    for (int j = 0; j < 4; j++){
      W[l][j]  = (const float*)d_in[2 + l*8 + j];      // Wq,Wk,Wv,Ws
      Bw[l][j] = (const float*)d_in[2 + l*8 + 4 + j];  // bq,bk,bv,bs
    }
    lng[l] = (const float*)d_in[34 + 2*l];
    lnb[l] = (const float*)d_in[35 + 2*l];
  }
  const float* fcW = (const float*)d_in[42];
  const float* fcB = (const float*)d_in[43];

  // ---- workspace (~52 MB of ~256 MiB) --------------------------------------
  char* ws = (char*)d_ws;
  size_t o = 0;
  auto alloc = [&](size_t bytes)->void*{ void* p = ws + o; o += (bytes + 255)/256*256; return p; };
  bf16* Hb   = (bf16*)alloc((size_t)MP*256*2);
  bf16* H2b  = (bf16*)alloc((size_t)MP*64*2);
  bf16* Qb   = (bf16*)alloc((size_t)MP*256*2);
  bf16* KVb  = (bf16*)alloc((size_t)MP*512*2);   // interleaved K|V rows
  bf16* LOG  = (bf16*)alloc((size_t)NE*8*2);
  int* OFFS  = (int*)alloc((size_t)(NN+1)*4);
  int* CNT   = (int*)alloc((size_t)(NN+1)*4);
  int* CURS  = (int*)alloc((size_t)(NN+1)*4);
  int* PERM  = (int*)alloc((size_t)NE*4);
  int* SRCS  = (int*)alloc((size_t)(NE+16)*4);
  bf16* WPK  = (bf16*)alloc((size_t)393216*2);
  size_t need = o;

  float* out_x  = (float*)d_out;                 // [NN,10]
  float* out_h4 = out_x + (size_t)NN*10;         // [NN,128]
  float* out_at = out_h4 + (size_t)NN*128;       // [NE,8]

  if (ws_size < need){
    fill_k<<<((size_t)out_size+255)/256, 256, 0, stream>>>((float*)d_out, out_size, 160.0f);
    return;
  }

  // ---- pack all 16 weights in ONE launch -----------------------------------
  const int KD[4] = {128,256,64,256};
  const int DD[4] = {256,64,256,128};
  PackArgs pa;
  bf16* Wp[4][4];
  {
    size_t off = 0;
    for (int l = 0; l < 4; l++)
      for (int j = 0; j < 4; j++){
        int idx = l*4 + j;
        pa.w[idx] = W[l][j];
        pa.off[idx] = off;
        pa.K[idx] = KD[l];
        pa.D[idx] = DD[l];
        Wp[l][j] = WPK + off;
        off += (size_t)KD[l]*DD[l];
      }
  }
  pack_all<<<dim3(128,16),256,0,stream>>>(pa, WPK);

  // ---- CSR by dst -----------------------------------------------------------
  hipMemsetAsync(CNT, 0, (size_t)NN*4, stream);
  count_k<<<NE/256, 256, 0, stream>>>(ei, CNT, NE);
  exscan_k<<<1, 1024, 0, stream>>>(CNT, OFFS, CURS, NN);
  scatter_k<<<NE/256, 256, 0, stream>>>(ei, CURS, PERM, SRCS, NE);

  const float s32  = 0.1767766952966369f;
  const float s8   = 0.3535533905932738f;
  const float s128 = 0.0883883476483184f;
  const dim3 g64(1, MP/64), g128(2, MP/64), g256(4, MP/64);

  // ---- L1: 128 -> 256, H=8 (4 head-group waves/node + standalone GELU/LN) --
  gemm_qkvs<float,bf16><<<g256,256,0,stream>>>(x,
      (const short8v*)Wp[0][0], (const short8v*)Wp[0][1],
      (const short8v*)Wp[0][2], (const short8v*)Wp[0][3],
      Bw[0][0], Bw[0][1], Bw[0][2], Bw[0][3],
      Qb, KVb, KVb + 256, Hb, 128, 16, 256, 512, 256, MP);
  attn_hg<256,8,4><<<dim3(NN/4,4),256,0,stream>>>(Qb, KVb, SRCS, OFFS, Hb, s32);
  gelu_ln<4><<<NN/4,256,0,stream>>>(Hb, lng[0], lnb[0]);

  // ---- L2: 256 -> 64, H=8 (fused epilogue + alpha) -------------------------
  gemm_qkvs<bf16,bf16><<<g64,256,0,stream>>>(Hb,
      (const short8v*)Wp[1][0], (const short8v*)Wp[1][1],
      (const short8v*)Wp[1][2], (const short8v*)Wp[1][3],
      Bw[1][0], Bw[1][1], Bw[1][2], Bw[1][3],
      Qb, KVb, KVb + 64, H2b, 256, 4, 64, 128, 64, MP);
  fused_attn<64,8,bf16><<<NN/4,256,0,stream>>>(Qb, KVb, SRCS, OFFS, H2b, 64,
      lng[1], lnb[1], LOG, PERM, out_at, s8);

  // fc on h2 (independent of L3/L4)
  fc_k<<<NN/4,256,0,stream>>>(H2b, fcW, fcB, out_x, 64, 10);

  // ---- L3: 64 -> 256, H=8 (head-group split) -------------------------------
  gemm_qkvs<bf16,bf16><<<g256,256,0,stream>>>(H2b,
      (const short8v*)Wp[2][0], (const short8v*)Wp[2][1],
      (const short8v*)Wp[2][2], (const short8v*)Wp[2][3],
      Bw[2][0], Bw[2][1], Bw[2][2], Bw[2][3],
      Qb, KVb, KVb + 256, Hb, 64, 16, 256, 512, 256, MP);
  attn_hg<256,8,4><<<dim3(NN/4,4),256,0,stream>>>(Qb, KVb, SRCS, OFFS, Hb, s32);
  gelu_ln<4><<<NN/4,256,0,stream>>>(Hb, lng[2], lnb[2]);

  // ---- L4: 256 -> 128, H=1 (fused epilogue) --------------------------------
  gemm_qkvs<bf16,float><<<g128,256,0,stream>>>(Hb,
      (const short8v*)Wp[3][0], (const short8v*)Wp[3][1],
      (const short8v*)Wp[3][2], (const short8v*)Wp[3][3],
      Bw[3][0], Bw[3][1], Bw[3][2], Bw[3][3],
      Qb, KVb, KVb + 128, out_h4, 256, 8, 128, 256, 128, NN);
  fused_attn<128,1,float><<<NN/4,256,0,stream>>>(Qb, KVb, SRCS, OFFS, out_h4, 128,
      lng[3], lnb[3], nullptr, nullptr, nullptr, s128);
}

// Round 18
// 331.913 us; speedup vs baseline: 1.0533x; 1.0533x over previous
//
#include <hip/hip_runtime.h>
#include <hip/hip_bf16.h>
#include <math.h>

#define NN 20000
#define MP 20032            // NN padded to 64 (MFMA row tiles)
#define NE 320000

typedef __hip_bfloat16 bf16;
typedef __attribute__((ext_vector_type(8))) short short8v;   // 8 bf16 (4 VGPR)
typedef __attribute__((ext_vector_type(4))) short short4v;
typedef __attribute__((ext_vector_type(4))) float f32x4;

__device__ __forceinline__ float b2f(bf16 v){ return __bfloat162float(v); }
__device__ __forceinline__ bf16 f2b(float v){ return __float2bfloat16(v); }
__device__ __forceinline__ float bfbits(short s){
  return __uint_as_float(((unsigned)(unsigned short)s) << 16);
}
__device__ __forceinline__ int clampi(int v, int lo, int hi){ return v < lo ? lo : (v > hi ? hi : v); }
__device__ __forceinline__ void stv(bf16* p, float v){ *p = f2b(v); }
__device__ __forceinline__ void stv(float* p, float v){ *p = v; }
__device__ __forceinline__ float ldv(const bf16* p){ return b2f(*p); }
__device__ __forceinline__ float ldv(const float* p){ return *p; }

// fast erf: Abramowitz-Stegun 7.1.26, |err| <= 1.5e-7 (well under bf16 ulp)
__device__ __forceinline__ float fast_erf(float x){
  float ax = fabsf(x);
  float t = __builtin_amdgcn_rcpf(1.f + 0.3275911f*ax);
  float p = ((((1.061405429f*t - 1.453152027f)*t + 1.421413741f)*t
              - 0.284496736f)*t + 0.254829592f)*t;
  float y = 1.f - p*__expf(-ax*ax);
  return copysignf(y, x);
}
__device__ __forceinline__ float gelu(float x){
  return 0.5f*x*(1.f + fast_erf(x*0.70710678118654752f));
}

// vector row loader: CPL consecutive bf16 -> f32
template<int CPL>
__device__ __forceinline__ void ldrow(const bf16* p, float* o){
  if constexpr (CPL == 16){
    short8v v0 = *reinterpret_cast<const short8v*>(p);
    short8v v1 = *reinterpret_cast<const short8v*>(p + 8);
#pragma unroll
    for (int j = 0; j < 8; j++){ o[j] = bfbits(v0[j]); o[8+j] = bfbits(v1[j]); }
  } else if constexpr (CPL == 8){
    short8v v = *reinterpret_cast<const short8v*>(p);
#pragma unroll
    for (int j = 0; j < 8; j++) o[j] = bfbits(v[j]);
  } else {
    short4v v = *reinterpret_cast<const short4v*>(p);
#pragma unroll
    for (int j = 0; j < 4; j++) o[j] = bfbits(v[j]);
  }
}
// overloads for the epilogue skip-row read (bf16 or f32 source)
template<int CPL>
__device__ __forceinline__ void ldrowT(const bf16* p, float* o){ ldrow<CPL>(p, o); }
template<int CPL>
__device__ __forceinline__ void ldrowT(const float* p, float* o){
#pragma unroll
  for (int j = 0; j < CPL; j += 4){
    float4 v = *reinterpret_cast<const float4*>(p + j);
    o[j] = v.x; o[j+1] = v.y; o[j+2] = v.z; o[j+3] = v.w;
  }
}

// A-fragment loaders (8 consecutive-k elems per lane)
__device__ __forceinline__ short8v ldA8(const bf16* p){
  return *reinterpret_cast<const short8v*>(p);
}
__device__ __forceinline__ short8v ldA8(const float* p){
  float4 a0 = *reinterpret_cast<const float4*>(p);
  float4 a1 = *reinterpret_cast<const float4*>(p + 4);
  short8v r;
  bf16 b;
  b = f2b(a0.x); r[0] = *(const short*)&b;
  b = f2b(a0.y); r[1] = *(const short*)&b;
  b = f2b(a0.z); r[2] = *(const short*)&b;
  b = f2b(a0.w); r[3] = *(const short*)&b;
  b = f2b(a1.x); r[4] = *(const short*)&b;
  b = f2b(a1.y); r[5] = *(const short*)&b;
  b = f2b(a1.z); r[6] = *(const short*)&b;
  b = f2b(a1.w); r[7] = *(const short*)&b;
  return r;
}

// ---- diagnostic fill ------------------------------------------------------
__global__ void fill_k(float* __restrict__ out, int n, float val){
  int i = blockIdx.x*blockDim.x + threadIdx.x;
  if (i < n) out[i] = val;
}

// ---- all-weights pack: f32 [K x D] -> MFMA B-fragment order bf16 -----------
struct PackArgs {
  const float* w[16];
  unsigned long long off[16];
  int K[16];
  int D[16];
};
__global__ void pack_all(PackArgs pa, bf16* __restrict__ out){
  int wi = blockIdx.y;
  int K = pa.K[wi], D = pa.D[wi];
  int i = blockIdx.x*256 + threadIdx.x;
  if (i >= K*D) return;
  int j = i & 7, l = (i >> 3) & 63;
  int TG = D >> 4;
  int tg = (i >> 9) % TG, s = (i >> 9) / TG;
  int k = s*32 + (l >> 4)*8 + j, n = tg*16 + (l & 15);
  out[pa.off[wi] + i] = f2b(pa.w[wi][(size_t)k*D + n]);
}

// ---- fused QKVS MFMA GEMM: 4 outputs sharing the A matrix ------------------
template<typename AT, typename TS>
__global__ void gemm_qkvs(const AT* __restrict__ X,
    const short8v* __restrict__ WQ, const short8v* __restrict__ WK,
    const short8v* __restrict__ WV, const short8v* __restrict__ WS,
    const float* __restrict__ bQ, const float* __restrict__ bK,
    const float* __restrict__ bV, const float* __restrict__ bS,
    bf16* __restrict__ Qo, bf16* __restrict__ Ko, bf16* __restrict__ Vo,
    TS* __restrict__ So,
    int K, int TG, int ldQKV, int ldS, int MstoreS){
  int w = threadIdx.x >> 6, lane = threadIdx.x & 63;
  int n0 = blockIdx.x*64;
  size_t m0 = (size_t)blockIdx.y*64 + w*16;
  int lr = lane & 15, lk = lane >> 4;
  int ar = clampi((int)(m0 + lr), 0, NN-1);
  const AT* xp = X + (size_t)ar*K + lk*8;
  size_t wo = ((size_t)(n0 >> 4))*64 + lane;
  f32x4 acc[4][4];
#pragma unroll
  for (int j = 0; j < 4; j++)
#pragma unroll
    for (int t = 0; t < 4; t++) acc[j][t] = f32x4{0,0,0,0};
  int steps = K >> 5;
  for (int s = 0; s < steps; s++){
    short8v a = ldA8(xp + s*32);
    size_t ro = wo + (size_t)s*TG*64;
#pragma unroll
    for (int t = 0; t < 4; t++){
      size_t idx = ro + t*64;
      acc[0][t] = __builtin_amdgcn_mfma_f32_16x16x32_bf16(a, WQ[idx], acc[0][t], 0, 0, 0);
      acc[1][t] = __builtin_amdgcn_mfma_f32_16x16x32_bf16(a, WK[idx], acc[1][t], 0, 0, 0);
      acc[2][t] = __builtin_amdgcn_mfma_f32_16x16x32_bf16(a, WV[idx], acc[2][t], 0, 0, 0);
      acc[3][t] = __builtin_amdgcn_mfma_f32_16x16x32_bf16(a, WS[idx], acc[3][t], 0, 0, 0);
    }
  }
#pragma unroll
  for (int t = 0; t < 4; t++){
    int col = n0 + t*16 + lr;
    float b0 = bQ[col], b1 = bK[col], b2 = bV[col], b3 = bS[col];
#pragma unroll
    for (int r = 0; r < 4; r++){
      size_t row = m0 + lk*4 + r;
      Qo[row*ldQKV + col] = f2b(acc[0][t][r] + b0);
      Ko[row*ldQKV + col] = f2b(acc[1][t][r] + b1);
      Vo[row*ldQKV + col] = f2b(acc[2][t][r] + b2);
      if ((int)row < MstoreS) stv(&So[row*(size_t)ldS + col], acc[3][t][r] + b3);
    }
  }
}

// ---- CSR build -------------------------------------------------------------
__global__ void count_k(const int* __restrict__ ei, int* __restrict__ cnt, int E){
  int e = blockIdx.x*blockDim.x + threadIdx.x;
  if (e < E){
    int d = clampi(ei[E + e], 0, NN-1);
    atomicAdd(&cnt[d], 1);
  }
}

__global__ void exscan_k(const int* __restrict__ cnt, int* __restrict__ off,
                         int* __restrict__ cur, int n){
  __shared__ int wtot[16];
  __shared__ int carrysh;
  int tid = threadIdx.x, lane = tid & 63, w = tid >> 6;
  if (tid == 0) carrysh = 0;
  __syncthreads();
  for (int base = 0; base < n; base += 1024){
    int i = base + tid;
    int v = (i < n) ? cnt[i] : 0;
    int s = v;
#pragma unroll
    for (int d = 1; d < 64; d <<= 1){
      int t = __shfl_up(s, d);
      if (lane >= d) s += t;
    }
    if (lane == 63) wtot[w] = s;
    __syncthreads();
    int woff = 0;
    for (int j = 0; j < w; j++) woff += wtot[j];
    int c = carrysh;
    if (i < n){ int val = c + woff + s - v; off[i] = val; cur[i] = val; }
    __syncthreads();
    if (tid == 1023) carrysh = c + woff + s;
    __syncthreads();
  }
  if (threadIdx.x == 0) off[n] = carrysh;
}

__global__ void scatter_k(const int* __restrict__ ei, int* __restrict__ cur,
                          int* __restrict__ perm, int* __restrict__ srcs, int E){
  int e = blockIdx.x*blockDim.x + threadIdx.x;
  if (e >= E) return;
  int s = clampi(ei[e], 0, NN-1);
  int d = clampi(ei[E + e], 0, NN-1);
  int p = atomicAdd(&cur[d], 1);
  if (p >= 0 && p < E){ perm[p] = e; srcs[p] = s; }
}

// ---- fused per-node attention + GELU/LN epilogue (+optional alpha out) -----
// Max-free softmax (logits O(10) by construction: LN'd inputs x 0.05 weights).
// ONE WAVE PER BLOCK (64 thr): independent retirement, better CU backfill.
// 4 slots of 16 lanes = 4 edges in flight (+1 prefetch pair).
template<int D, int H, typename TO>
__global__ void fused_attn(const bf16* __restrict__ Q, const bf16* __restrict__ Kf,
                           const bf16* __restrict__ V, const int* __restrict__ srcs,
                           const int* __restrict__ offs,
                           TO* __restrict__ Xout, int ldO,
                           const float* __restrict__ G, const float* __restrict__ Bt,
                           bf16* __restrict__ LOG, const int* __restrict__ perm,
                           float* __restrict__ attn_out, float scale){
  constexpr int CPL = D/16;       // channels per lane (quarter-wave of 16)
  constexpr int LPH = 16/H;       // lanes per head within a slot
  int node = blockIdx.x;
  int lane = threadIdx.x & 63;
  int hl = lane & 15;
  int slot = lane >> 4;
  float q[CPL];
  {
    float tmp[CPL];
    ldrow<CPL>(Q + (size_t)node*D + hl*CPL, tmp);
#pragma unroll
    for (int j = 0; j < CPL; j++) q[j] = tmp[j] * scale;
  }
  float den = 0.f;
  float acc[CPL];
#pragma unroll
  for (int j = 0; j < CPL; j++) acc[j] = 0.f;
  int s0 = offs[node], e0 = offs[node+1];
  int i = s0 + slot;
  bool vcur = i < e0;
  int sc = vcur ? srcs[i] : 0;
  float kc[CPL], vc[CPL];
  ldrow<CPL>(Kf + (size_t)sc*D + hl*CPL, kc);
  ldrow<CPL>(V  + (size_t)sc*D + hl*CPL, vc);
  int iters = (e0 - s0 + 3) >> 2;
  for (int it = 0; it < iters; ++it){
    int inext = i + 4;
    bool vnxt = inext < e0;
    int sn = vnxt ? srcs[inext] : 0;
    float kn[CPL], vn[CPL];
    ldrow<CPL>(Kf + (size_t)sn*D + hl*CPL, kn);
    ldrow<CPL>(V  + (size_t)sn*D + hl*CPL, vn);
    float t = 0.f;
#pragma unroll
    for (int j = 0; j < CPL; j++) t += q[j]*kc[j];
#pragma unroll
    for (int o = 1; o < LPH; o <<= 1) t += __shfl_xor(t, o);
    if (LOG && vcur && ((hl & (LPH-1)) == 0)) LOG[(size_t)i*H + hl/LPH] = f2b(t);
    float pe = vcur ? __expf(t) : 0.f;
    den += pe;
#pragma unroll
    for (int j = 0; j < CPL; j++) acc[j] += pe*vc[j];
    vcur = vnxt; i = inext;
#pragma unroll
    for (int j = 0; j < CPL; j++){ kc[j] = kn[j]; vc[j] = vn[j]; }
  }
  // merge slots (butterfly -> every lane has full den/acc)
  den += __shfl_xor(den, 16);
  den += __shfl_xor(den, 32);
#pragma unroll
  for (int j = 0; j < CPL; j++){
    acc[j] += __shfl_xor(acc[j], 16);
    acc[j] += __shfl_xor(acc[j], 32);
  }
  float inv = 1.f/(den + 1e-16f);

  // ---- GELU + LayerNorm epilogue (fast erf; full row per 16-lane group) ----
  {
    float sk[CPL];
    ldrowT<CPL>(Xout + (size_t)node*ldO + hl*CPL, sk);
    float v[CPL]; float s = 0.f;
#pragma unroll
    for (int j = 0; j < CPL; j++){
      float ge = gelu(sk[j] + acc[j]*inv);       // skip + aggregated
      v[j] = ge; s += ge;
    }
#pragma unroll
    for (int o = 1; o < 16; o <<= 1) s += __shfl_xor(s, o);
    float mu = s * (1.f/D);
    float qv = 0.f;
#pragma unroll
    for (int j = 0; j < CPL; j++){ float d2 = v[j]-mu; qv += d2*d2; }
#pragma unroll
    for (int o = 1; o < 16; o <<= 1) qv += __shfl_xor(qv, o);
    float lni = 1.f / sqrtf(qv*(1.f/D) + 1e-5f);
    if (slot == 0){
      TO* oo = Xout + (size_t)node*ldO + hl*CPL;
#pragma unroll
      for (int j = 0; j < CPL; j++){
        int c = hl*CPL + j;
        stv(&oo[j], G[c]*(v[j]-mu)*lni + Bt[c]);
      }
    }
  }

  // ---- alpha scatter epilogue (L2 only) ------------------------------------
  if (attn_out){
    asm volatile("s_waitcnt vmcnt(0)" ::: "memory");   // LOG stores visible
    int total = (e0 - s0) * H;
    int it2 = (total + 63) >> 6;
    for (int b = 0; b < it2; b++){
      int idx = b*64 + lane;
      int h = idx & (H-1);
      float dh = __shfl(den, h*LPH);
      if (idx < total){
        int pos = s0 + (idx >> 3);
        float lg = b2f(LOG[(size_t)pos*H + h]);
        attn_out[(size_t)perm[pos]*H + h] = __expf(lg)/(dh + 1e-16f);
      }
    }
  }
}

// ---- tiny fc ----------------------------------------------------------------
__global__ void fc_k(const bf16* __restrict__ X, const float* __restrict__ W,
                     const float* __restrict__ B, float* __restrict__ Out,
                     int K, int D){
  int m = blockIdx.x*4 + (threadIdx.x >> 6);
  int lane = threadIdx.x & 63;
  if (m >= NN || lane >= D) return;
  float acc = B[lane];
  for (int k = 0; k < K; k++) acc += b2f(X[(size_t)m*K + k]) * W[(size_t)k*D + lane];
  Out[(size_t)m*D + lane] = acc;
}

extern "C" void kernel_launch(void* const* d_in, const int* in_sizes, int n_in,
                              void* d_out, int out_size, void* d_ws, size_t ws_size,
                              hipStream_t stream){
  int code = 0;
  if (n_in != 44) code = 100;
  else {
    const int wsz[4] = {32768,16384,16384,32768};
    const int bsz[4] = {256,64,256,128};
    bool ok = in_sizes[0] == NN*128 && in_sizes[1] == 2*NE
           && in_sizes[42] == 640 && in_sizes[43] == 10;
    for (int l = 0; l < 4 && ok; l++){
      for (int j = 0; j < 4; j++)
        ok = ok && in_sizes[2+l*8+j] == wsz[l] && in_sizes[2+l*8+4+j] == bsz[l];
      ok = ok && in_sizes[34+2*l] == bsz[l] && in_sizes[35+2*l] == bsz[l];
    }
    if (!ok) code = 140;
  }
  if (code){
    fill_k<<<((size_t)out_size+255)/256, 256, 0, stream>>>((float*)d_out, out_size, (float)code);
    return;
  }

  const float* x = (const float*)d_in[0];
  const int*   ei = (const int*)d_in[1];
  const float *W[4][4], *Bw[4][4], *lng[4], *lnb[4];
  for (int l = 0; l < 4; l++){
    for (int j = 0; j < 4; j++){
      W[l][j]  = (const float*)d_in[2 + l*8 + j];      // Wq,Wk,Wv,Ws
      Bw[l][j] = (const float*)d_in[2 + l*8 + 4 + j];  // bq,bk,bv,bs
    }
    lng[l] = (const float*)d_in[34 + 2*l];
    lnb[l] = (const float*)d_in[35 + 2*l];
  }
  const float* fcW = (const float*)d_in[42];
  const float* fcB = (const float*)d_in[43];

  // ---- workspace (~52 MB of ~256 MiB) --------------------------------------
  char* ws = (char*)d_ws;
  size_t o = 0;
  auto alloc = [&](size_t bytes)->void*{ void* p = ws + o; o += (bytes + 255)/256*256; return p; };
  bf16* Hb   = (bf16*)alloc((size_t)MP*256*2);
  bf16* H2b  = (bf16*)alloc((size_t)MP*64*2);
  bf16* Qb   = (bf16*)alloc((size_t)MP*256*2);
  bf16* Kb   = (bf16*)alloc((size_t)MP*256*2);
  bf16* Vb   = (bf16*)alloc((size_t)MP*256*2);
  bf16* LOG  = (bf16*)alloc((size_t)NE*8*2);
  int* OFFS  = (int*)alloc((size_t)(NN+1)*4);
  int* CNT   = (int*)alloc((size_t)(NN+1)*4);
  int* CURS  = (int*)alloc((size_t)(NN+1)*4);
  int* PERM  = (int*)alloc((size_t)NE*4);
  int* SRCS  = (int*)alloc((size_t)NE*4);
  bf16* WPK  = (bf16*)alloc((size_t)393216*2);
  size_t need = o;

  float* out_x  = (float*)d_out;                 // [NN,10]
  float* out_h4 = out_x + (size_t)NN*10;         // [NN,128]
  float* out_at = out_h4 + (size_t)NN*128;       // [NE,8]

  if (ws_size < need){
    fill_k<<<((size_t)out_size+255)/256, 256, 0, stream>>>((float*)d_out, out_size, 160.0f);
    return;
  }

  // ---- pack all 16 weights in ONE launch -----------------------------------
  const int KD[4] = {128,256,64,256};
  const int DD[4] = {256,64,256,128};
  PackArgs pa;
  bf16* Wp[4][4];
  {
    size_t off = 0;
    for (int l = 0; l < 4; l++)
      for (int j = 0; j < 4; j++){
        int idx = l*4 + j;
        pa.w[idx] = W[l][j];
        pa.off[idx] = off;
        pa.K[idx] = KD[l];
        pa.D[idx] = DD[l];
        Wp[l][j] = WPK + off;
        off += (size_t)KD[l]*DD[l];
      }
  }
  pack_all<<<dim3(128,16),256,0,stream>>>(pa, WPK);

  // ---- CSR by dst -----------------------------------------------------------
  hipMemsetAsync(CNT, 0, (size_t)NN*4, stream);
  count_k<<<NE/256, 256, 0, stream>>>(ei, CNT, NE);
  exscan_k<<<1, 1024, 0, stream>>>(CNT, OFFS, CURS, NN);
  scatter_k<<<NE/256, 256, 0, stream>>>(ei, CURS, PERM, SRCS, NE);

  const float s32  = 0.1767766952966369f;
  const float s8   = 0.3535533905932738f;
  const float s128 = 0.0883883476483184f;
  const dim3 g64(1, MP/64), g128(2, MP/64), g256(4, MP/64);

  // ---- L1: 128 -> 256, H=8 -------------------------------------------------
  gemm_qkvs<float,bf16><<<g256,256,0,stream>>>(x,
      (const short8v*)Wp[0][0], (const short8v*)Wp[0][1],
      (const short8v*)Wp[0][2], (const short8v*)Wp[0][3],
      Bw[0][0], Bw[0][1], Bw[0][2], Bw[0][3],
      Qb, Kb, Vb, Hb, 128, 16, 256, 256, MP);
  fused_attn<256,8,bf16><<<NN,64,0,stream>>>(Qb,Kb,Vb, SRCS,OFFS, Hb,256,
      lng[0],lnb[0], nullptr,nullptr,nullptr, s32);

  // ---- L2: 256 -> 64, H=8 (alpha folded in) --------------------------------
  gemm_qkvs<bf16,bf16><<<g64,256,0,stream>>>(Hb,
      (const short8v*)Wp[1][0], (const short8v*)Wp[1][1],
      (const short8v*)Wp[1][2], (const short8v*)Wp[1][3],
      Bw[1][0], Bw[1][1], Bw[1][2], Bw[1][3],
      Qb, Kb, Vb, H2b, 256, 4, 64, 64, MP);
  fused_attn<64,8,bf16><<<NN,64,0,stream>>>(Qb,Kb,Vb, SRCS,OFFS, H2b,64,
      lng[1],lnb[1], LOG,PERM,out_at, s8);

  // fc on h2 (independent of L3/L4)
  fc_k<<<NN/4,256,0,stream>>>(H2b, fcW, fcB, out_x, 64, 10);

  // ---- L3: 64 -> 256, H=8 --------------------------------------------------
  gemm_qkvs<bf16,bf16><<<g256,256,0,stream>>>(H2b,
      (const short8v*)Wp[2][0], (const short8v*)Wp[2][1],
      (const short8v*)Wp[2][2], (const short8v*)Wp[2][3],
      Bw[2][0], Bw[2][1], Bw[2][2], Bw[2][3],
      Qb, Kb, Vb, Hb, 64, 16, 256, 256, MP);
  fused_attn<256,8,bf16><<<NN,64,0,stream>>>(Qb,Kb,Vb, SRCS,OFFS, Hb,256,
      lng[2],lnb[2], nullptr,nullptr,nullptr, s32);

  // ---- L4: 256 -> 128, H=1 -------------------------------------------------
  gemm_qkvs<bf16,float><<<g128,256,0,stream>>>(Hb,
      (const short8v*)Wp[3][0], (const short8v*)Wp[3][1],
      (const short8v*)Wp[3][2], (const short8v*)Wp[3][3],
      Bw[3][0], Bw[3][1], Bw[3][2], Bw[3][3],
      Qb, Kb, Vb, out_h4, 256, 8, 128, 128, NN);
  fused_attn<128,1,float><<<NN,64,0,stream>>>(Qb,Kb,Vb, SRCS,OFFS, out_h4,128,
      lng[3],lnb[3], nullptr,nullptr,nullptr, s128);
}